// Round 5
// baseline (335.348 us; speedup 1.0000x reference)
//
#include <hip/hip_runtime.h>

typedef __attribute__((ext_vector_type(8))) short short8;
typedef __attribute__((ext_vector_type(4))) float f32x4;

#define LSEQ   4096
#define NHEAD  8
#define DCH    64
#define HEIGHT 64
#define WIDTH  64

// ---------- helpers ----------
static __device__ __forceinline__ float bfu2f(unsigned short u) {
  return __uint_as_float(((unsigned int)u) << 16);
}
static __device__ __forceinline__ unsigned short f2bfu(float f) {
  unsigned int b = __float_as_uint(f);
  b += 0x7FFFu + ((b >> 16) & 1u);   // RNE
  return (unsigned short)(b >> 16);
}
static __device__ __forceinline__ float ldf(const void* p, int i, int isbf) {
  return isbf ? bfu2f(((const unsigned short*)p)[i]) : ((const float*)p)[i];
}
static __device__ __forceinline__ float softplus_inv(float sp) {
  float s = (sp > 20.f) ? sp : log1pf(expf(sp));
  return 1.f / s;
}
static __device__ __forceinline__ void unpack2(unsigned int u, float& lo, float& hi) {
  lo = __uint_as_float(u << 16);
  hi = __uint_as_float(u & 0xFFFF0000u);
}
// load 8 consecutive channels as floats (b128 for bf16, 2x b128 for fp32)
static __device__ __forceinline__ void load8(const void* p, int gi, int isbf, float o[8]) {
  if (isbf) {
    uint4 u = *(const uint4*)((const unsigned short*)p + gi);
    unpack2(u.x, o[0], o[1]); unpack2(u.y, o[2], o[3]);
    unpack2(u.z, o[4], o[5]); unpack2(u.w, o[6], o[7]);
  } else {
    const float4* f4 = (const float4*)((const float*)p + gi);
    float4 a = f4[0], b = f4[1];
    o[0]=a.x; o[1]=a.y; o[2]=a.z; o[3]=a.w;
    o[4]=b.x; o[5]=b.y; o[6]=b.z; o[7]=b.w;
  }
}
// reduce over the 8 lanes sharing a row (xor masks 1,2,4)
static __device__ __forceinline__ void row_reduce2(float& a, float& b) {
  #pragma unroll
  for (int m = 1; m < 8; m <<= 1) { a += __shfl_xor(a, m, 64); b += __shfl_xor(b, m, 64); }
}
static __device__ __forceinline__ float row_reduce1(float a) {
  #pragma unroll
  for (int m = 1; m < 8; m <<= 1) a += __shfl_xor(a, m, 64);
  return a;
}

// ---------- dtype detection ----------
__global__ void detect_kernel(const unsigned int* __restrict__ q, int* __restrict__ flag) {
  int lane = threadIdx.x & 63;
  int hits = 0;
  #pragma unroll
  for (int i = 0; i < 4; ++i) {
    unsigned int lo = q[lane * 4 + i] & 0xFFFFu;
    unsigned int e  = (lo >> 7) & 0xFFu;
    if (lo == 0u || (e >= 110u && e <= 140u)) hits++;
  }
  #pragma unroll
  for (int m = 1; m < 64; m <<= 1) hits += __shfl_xor(hits, m, 64);
  if (lane == 0) *flag = (hits > 128) ? 1 : 0;
}

// ---------- kv kernel ----------
// R5: TLP instead of deep per-block pipelining. chunks=64 -> 4096 blocks
// (16/CU queued), nsub=2 so the per-block serial chain is prologue + one
// pair-iteration; barrier/HBM stalls are covered by other resident blocks.
// Keeps depth-2 register prefetch + double-buffered LDS, one barrier/subtile.
// LDS layout: transposed [d][s'] with s' = s ^ (((d>>3)&3)<<3).
__global__ __launch_bounds__(256) void kv_kernel(
    const void* __restrict__ keys, const void* __restrict__ values,
    const void* __restrict__ scale_param,
    float* __restrict__ kv_p, float* __restrict__ ksum_g,
    const int* __restrict__ flagp, int chunks, int rows)
{
  __shared__ __align__(16) unsigned short kfT[2][64 * 40];
  __shared__ __align__(16) unsigned short vvT[2][64 * 40];
  __shared__ float red[256];

  const int isbf = *flagp;
  const int b = blockIdx.x;
  const int chunk = b % chunks;
  const int nh = b / chunks;
  const int h = nh & 7, n = nh >> 3;
  const int t = threadIdx.x, lane = t & 63, wid = t >> 6;
  const int quad = lane >> 4, m16 = lane & 15;
  const int r = lane >> 3, c = lane & 7, d0 = c * 8;
  const int s_local = wid * 8 + r;
  const int sp = s_local ^ ((c & 3) << 3);

  float inv_s[8];
  #pragma unroll
  for (int i = 0; i < 8; ++i) inv_s[i] = softplus_inv(ldf(scale_param, d0 + i, isbf));

  f32x4 acc[4];
  #pragma unroll
  for (int mt = 0; mt < 4; ++mt) acc[mt] = (f32x4){0.f, 0.f, 0.f, 0.f};
  float ksum_acc[8];
  #pragma unroll
  for (int i = 0; i < 8; ++i) ksum_acc[i] = 0.f;

  const int nsub = rows >> 5;     // >= 2 and even for chunks <= 64
  const int npair = nsub >> 1;

  // issue global loads for subtile `sub` into a named register slot
  auto issue = [&](uint4& K0, uint4& K1, uint4& V0, uint4& V1, int sub) {
    const int s = chunk * rows + sub * 32 + s_local;
    const int gi = ((n * LSEQ + s) * NHEAD + h) * DCH + d0;
    if (isbf) {
      K0 = *(const uint4*)((const unsigned short*)keys + gi);
      V0 = *(const uint4*)((const unsigned short*)values + gi);
    } else {
      const uint4* kp = (const uint4*)((const float*)keys + gi);
      K0 = kp[0]; K1 = kp[1];
      const uint4* vp = (const uint4*)((const float*)values + gi);
      V0 = vp[0]; V1 = vp[1];
    }
  };
  auto tofloat8 = [&](uint4 A, uint4 B, float o[8]) {
    if (isbf) {
      unpack2(A.x, o[0], o[1]); unpack2(A.y, o[2], o[3]);
      unpack2(A.z, o[4], o[5]); unpack2(A.w, o[6], o[7]);
    } else {
      o[0]=__uint_as_float(A.x); o[1]=__uint_as_float(A.y);
      o[2]=__uint_as_float(A.z); o[3]=__uint_as_float(A.w);
      o[4]=__uint_as_float(B.x); o[5]=__uint_as_float(B.y);
      o[6]=__uint_as_float(B.z); o[7]=__uint_as_float(B.w);
    }
  };
  // normalize + ksum + transposed LDS write into buffer `buf`
  auto process = [&](uint4 K0, uint4 K1, uint4 V0, uint4 V1, int buf) {
    float kraw[8];
    tofloat8(K0, K1, kraw);
    float xv[8], yv[8], s2 = 0.f, s6 = 0.f;
    #pragma unroll
    for (int i = 0; i < 8; ++i) {
      xv[i] = (fmaxf(kraw[i], 0.f) + 1e-6f) * inv_s[i];
      s2 += xv[i] * xv[i];
    }
    #pragma unroll
    for (int i = 0; i < 8; ++i) {
      yv[i] = xv[i] * xv[i] * xv[i];
      s6 += yv[i] * yv[i];
    }
    row_reduce2(s2, s6);
    const float coef = sqrtf(s2 / s6);
    #pragma unroll
    for (int i = 0; i < 8; ++i) {
      float f = yv[i] * coef;
      ksum_acc[i] += f;
      kfT[buf][(d0 + i) * 40 + sp] = f2bfu(f);
    }
    if (isbf) {
      unsigned short vs8[8];
      *(uint4*)vs8 = V0;
      #pragma unroll
      for (int i = 0; i < 8; ++i) vvT[buf][(d0 + i) * 40 + sp] = vs8[i];
    } else {
      float vraw[8];
      tofloat8(V0, V1, vraw);
      #pragma unroll
      for (int i = 0; i < 8; ++i) vvT[buf][(d0 + i) * 40 + sp] = f2bfu(vraw[i]);
    }
  };
  auto mfma_step = [&](int buf) {
    const int v = wid * 16 + m16;
    short8 bfr = *(const short8*)&vvT[buf][v * 40 + (quad ^ ((v >> 3) & 3)) * 8];
    #pragma unroll
    for (int mt = 0; mt < 4; ++mt) {
      int d = mt * 16 + m16;
      short8 afr = *(const short8*)&kfT[buf][d * 40 + (quad ^ ((d >> 3) & 3)) * 8];
      acc[mt] = __builtin_amdgcn_mfma_f32_16x16x32_bf16(afr, bfr, acc[mt], 0, 0, 0);
    }
  };

  // two named prefetch slots (A: even subs, B: odd subs) — static indexing only
  uint4 kA0, kA1, vA0, vA1;
  uint4 kB0, kB1, vB0, vB1;

  issue(kA0, kA1, vA0, vA1, 0);
  issue(kB0, kB1, vB0, vB1, 1);
  process(kA0, kA1, vA0, vA1, 0);
  __syncthreads();

  for (int p = 0; p < npair; ++p) {
    const int sub = 2 * p;
    // even sub: compute buf0; fill buf1 with sub+1; prefetch sub+2 into A
    if (sub + 2 < nsub) issue(kA0, kA1, vA0, vA1, sub + 2);
    mfma_step(0);
    process(kB0, kB1, vB0, vB1, 1);          // sub+1 always exists (nsub even)
    __syncthreads();
    // odd sub: compute buf1; fill buf0 with sub+2; prefetch sub+3 into B
    if (sub + 3 < nsub) issue(kB0, kB1, vB0, vB1, sub + 3);
    mfma_step(1);
    if (sub + 2 < nsub) process(kA0, kA1, vA0, vA1, 0);
    __syncthreads();
  }

  // fp32 partials: kv_p[chunk][nh][d][v]
  float* dst = kv_p + ((size_t)chunk * 64 + nh) * 4096;
  #pragma unroll
  for (int mt = 0; mt < 4; ++mt)
    #pragma unroll
    for (int rr = 0; rr < 4; ++rr) {
      int d = mt * 16 + quad * 4 + rr;
      dst[d * 64 + wid * 16 + m16] = acc[mt][rr];
    }

  // ksum: reduce across row-groups (masks 8,16,32), then block reduce + atomic
  #pragma unroll
  for (int i = 0; i < 8; ++i) {
    #pragma unroll
    for (int m = 8; m < 64; m <<= 1) ksum_acc[i] += __shfl_xor(ksum_acc[i], m, 64);
  }
  if (r == 0) {
    #pragma unroll
    for (int i = 0; i < 8; ++i) red[wid * 64 + d0 + i] = ksum_acc[i];
  }
  __syncthreads();
  if (t < 64) {
    float tot = red[t] + red[64 + t] + red[128 + t] + red[192 + t];
    atomicAdd(&ksum_g[nh * 64 + t], tot);
  }
}

// ---------- reduce: sum chunks, emit kv bf16 [nh][v][d] ----------
__global__ __launch_bounds__(256) void reduce_kernel(
    const float* __restrict__ kv_p, unsigned short* __restrict__ kvb, int chunks)
{
  int cidx = blockIdx.x * 256 + threadIdx.x;   // 0..262143
  int nh = cidx >> 12;
  int dv = cidx & 4095;
  int d = dv >> 6, v = dv & 63;
  float s = 0.f;
  for (int ch = 0; ch < chunks; ++ch)
    s += kv_p[((size_t)ch * 64 + nh) * 4096 + dv];
  kvb[(nh * 64 + v) * 64 + d] = f2bfu(s);
}

// ---------- attention kernel: per (n,h,y) MFMA O = (qf*z) @ kv ----------
__global__ __launch_bounds__(256) void attn_kernel(
    const void* __restrict__ queries, const unsigned short* __restrict__ kvb,
    const float* __restrict__ ksum_g, const void* __restrict__ scale_param,
    void* __restrict__ out, const int* __restrict__ flagp)
{
  __shared__ __align__(16) unsigned short qf[64 * 72];  // stride 36 dwords

  const int isbf = *flagp;
  const int b = blockIdx.x;
  const int y = b & 63;
  const int nh = b >> 6;
  const int h = nh & 7, n = nh >> 3;
  const int t = threadIdx.x, lane = t & 63, wid = t >> 6;
  const int quad = lane >> 4, m16 = lane & 15;
  const int r = lane >> 3, c = lane & 7, d0 = c * 8;

  float inv_s[8];
  #pragma unroll
  for (int i = 0; i < 8; ++i) inv_s[i] = softplus_inv(ldf(scale_param, d0 + i, isbf));
  float ks[8];
  {
    float4 k0 = *(const float4*)&ksum_g[nh * 64 + d0];
    float4 k1 = *(const float4*)&ksum_g[nh * 64 + d0 + 4];
    ks[0]=k0.x; ks[1]=k0.y; ks[2]=k0.z; ks[3]=k0.w;
    ks[4]=k1.x; ks[5]=k1.y; ks[6]=k1.z; ks[7]=k1.w;
  }

  // B fragments from global (L2-resident)
  const unsigned short* kvrow = kvb + (nh * 64 + wid * 16 + m16) * 64;
  short8 bfr0 = *(const short8*)&kvrow[quad * 8];
  short8 bfr1 = *(const short8*)&kvrow[32 + quad * 8];

  // stage qf: wave wid covers x = wid*16..+15 in 2 batches of 8 rows
  #pragma unroll
  for (int batch = 0; batch < 2; ++batch) {
    int x = wid * 16 + batch * 8 + r;
    int gi = ((n * LSEQ + y * 64 + x) * NHEAD + h) * DCH + d0;
    float qraw[8];
    load8(queries, gi, isbf, qraw);
    float xv[8], yv[8], s2 = 0.f, s6 = 0.f;
    #pragma unroll
    for (int i = 0; i < 8; ++i) {
      xv[i] = (fmaxf(qraw[i], 0.f) + 1e-6f) * inv_s[i];
      s2 += xv[i] * xv[i];
    }
    #pragma unroll
    for (int i = 0; i < 8; ++i) {
      yv[i] = xv[i] * xv[i] * xv[i];
      s6 += yv[i] * yv[i];
    }
    row_reduce2(s2, s6);
    const float coef = sqrtf(s2 / s6);
    float f[8], dot = 0.f;
    #pragma unroll
    for (int i = 0; i < 8; ++i) { f[i] = yv[i] * coef; dot += f[i] * ks[i]; }
    dot = row_reduce1(dot);
    const float z = 1.f / (dot + 1e-6f);
    uint4 pk;
    pk.x = (unsigned int)f2bfu(f[0] * z) | ((unsigned int)f2bfu(f[1] * z) << 16);
    pk.y = (unsigned int)f2bfu(f[2] * z) | ((unsigned int)f2bfu(f[3] * z) << 16);
    pk.z = (unsigned int)f2bfu(f[4] * z) | ((unsigned int)f2bfu(f[5] * z) << 16);
    pk.w = (unsigned int)f2bfu(f[6] * z) | ((unsigned int)f2bfu(f[7] * z) << 16);
    *(uint4*)&qf[x * 72 + d0] = pk;
  }
  __syncthreads();

  const size_t obase = (((size_t)n * LSEQ + y * 64) * NHEAD + h) * DCH;
  #pragma unroll
  for (int mt = 0; mt < 4; ++mt) {
    f32x4 acc = (f32x4){0.f, 0.f, 0.f, 0.f};
    short8 a0 = *(const short8*)&qf[(mt * 16 + m16) * 72 + quad * 8];
    short8 a1 = *(const short8*)&qf[(mt * 16 + m16) * 72 + 32 + quad * 8];
    acc = __builtin_amdgcn_mfma_f32_16x16x32_bf16(a0, bfr0, acc, 0, 0, 0);
    acc = __builtin_amdgcn_mfma_f32_16x16x32_bf16(a1, bfr1, acc, 0, 0, 0);
    #pragma unroll
    for (int rr = 0; rr < 4; ++rr) {
      int x = mt * 16 + quad * 4 + rr;
      int v = wid * 16 + m16;
      size_t oi = obase + (size_t)x * (NHEAD * DCH) + v;
      if (isbf) ((unsigned short*)out)[oi] = f2bfu(acc[rr]);
      else      ((float*)out)[oi] = acc[rr];
    }
  }
}

// ---------- conv kernel: depthwise 5x5 + bias, RMW on out ----------
// Channel-split: each block handles 32 of 64 channels for a 4-row slab.
// R5: compute/write thread remap xx=t>>2, jb=t&3 so lanes 0-3 RMW 64B
// contiguous (full sector) — was 16B at 1KB stride (WRITE_SIZE 65.5MB for a
// 33.5MB output). LDS read stays conflict-free: byte(l) = 16*l exactly
// (the jb XOR swizzle permutes within each 64B group).
__global__ __launch_bounds__(256) void conv_kernel(
    const void* __restrict__ values, const void* __restrict__ dwc_w,
    const void* __restrict__ dwc_b, void* __restrict__ out,
    const int* __restrict__ flagp)
{
  __shared__ __align__(16) unsigned short vs[8 * 64 * 32];  // 32 KB
  __shared__ float wl[25 * 32];   // [tap][32 ch]
  __shared__ float bl[32];

  const int isbf = *flagp;
  const int b = blockIdx.x;
  const int slab = b & 15;
  const int half = (b >> 4) & 1;
  const int nh = b >> 5;
  const int h = nh & 7, n = nh >> 3;
  const int y0 = slab * 4;
  const int t = threadIdx.x;

  // weights for this half: global flat idx = (half*32+dloc)*25 + tap
  for (int i = t; i < 800; i += 256) {
    int dloc = i / 25, tap = i - dloc * 25;
    wl[tap * 32 + dloc] = ldf(dwc_w, half * 800 + i, isbf);
  }
  if (t < 32) bl[t] = ldf(dwc_b, half * 32 + t, isbf);

  // stage 8 rows (y0-2 .. y0+5) x 64 x x 32 ch as bf16
  for (int it = t; it < 8 * 64 * 4; it += 256) {
    int j = it & 3;                  // 8-ch sub-group within the half
    int xx = (it >> 2) & 63;
    int rr = it >> 8;
    int yy = y0 - 2 + rr;
    int swz = j ^ (xx & 3) ^ ((xx >> 2) & 3);
    unsigned short* dst = &vs[((rr * 64 + xx) * 32) + swz * 8];
    if (yy >= 0 && yy < HEIGHT) {
      int gi = ((n * LSEQ + yy * 64 + xx) * NHEAD + h) * DCH + half * 32 + j * 8;
      if (isbf) {
        *(uint4*)dst = *(const uint4*)((const unsigned short*)values + gi);
      } else {
        const float4* s4 = (const float4*)((const float*)values + gi);
        float4 f0 = s4[0], f1 = s4[1];
        dst[0] = f2bfu(f0.x); dst[1] = f2bfu(f0.y);
        dst[2] = f2bfu(f0.z); dst[3] = f2bfu(f0.w);
        dst[4] = f2bfu(f1.x); dst[5] = f2bfu(f1.y);
        dst[6] = f2bfu(f1.z); dst[7] = f2bfu(f1.w);
      }
    } else {
      uint4 z; z.x = z.y = z.z = z.w = 0u;
      *(uint4*)dst = z;
    }
  }
  __syncthreads();

  const int xx = t >> 2, jb = t & 3;   // coalesced RMW: 4 lanes cover 64B
  float a[4][8];
  float bias8[8];
  {
    float4 b0 = *(const float4*)&bl[jb * 8];
    float4 b1 = *(const float4*)&bl[jb * 8 + 4];
    bias8[0]=b0.x; bias8[1]=b0.y; bias8[2]=b0.z; bias8[3]=b0.w;
    bias8[4]=b1.x; bias8[5]=b1.y; bias8[6]=b1.z; bias8[7]=b1.w;
  }
  #pragma unroll
  for (int rr = 0; rr < 4; ++rr)
    #pragma unroll
    for (int cc = 0; cc < 8; ++cc) a[rr][cc] = bias8[cc];

  for (int ky = 0; ky < 5; ++ky) {
    #pragma unroll
    for (int kx = 0; kx < 5; ++kx) {
      int xs = xx + kx - 2;
      if ((unsigned)xs < (unsigned)WIDTH) {
        float4 w0 = *(const float4*)&wl[(ky * 5 + kx) * 32 + jb * 8];
        float4 w1 = *(const float4*)&wl[(ky * 5 + kx) * 32 + jb * 8 + 4];
        int swz = jb ^ (xs & 3) ^ ((xs >> 2) & 3);
        #pragma unroll
        for (int rr = 0; rr < 4; ++rr) {
          uint4 pv = *(const uint4*)&vs[(((rr + ky) * 64 + xs) * 32) + swz * 8];
          float v0,v1,v2,v3,v4,v5,v6,v7;
          unpack2(pv.x, v0, v1); unpack2(pv.y, v2, v3);
          unpack2(pv.z, v4, v5); unpack2(pv.w, v6, v7);
          a[rr][0] += w0.x * v0; a[rr][1] += w0.y * v1;
          a[rr][2] += w0.z * v2; a[rr][3] += w0.w * v3;
          a[rr][4] += w1.x * v4; a[rr][5] += w1.y * v5;
          a[rr][6] += w1.z * v6; a[rr][7] += w1.w * v7;
        }
      }
    }
  }
  #pragma unroll
  for (int rr = 0; rr < 4; ++rr) {
    size_t oi = (((size_t)n * LSEQ + (y0 + rr) * 64 + xx) * NHEAD + h) * DCH
              + half * 32 + jb * 8;
    if (isbf) {
      unsigned short* op = (unsigned short*)out + oi;
      uint4 cur = *(uint4*)op;
      float c0,c1,c2,c3,c4,c5,c6,c7;
      unpack2(cur.x, c0, c1); unpack2(cur.y, c2, c3);
      unpack2(cur.z, c4, c5); unpack2(cur.w, c6, c7);
      uint4 res;
      res.x = (unsigned int)f2bfu(c0 + a[rr][0]) | ((unsigned int)f2bfu(c1 + a[rr][1]) << 16);
      res.y = (unsigned int)f2bfu(c2 + a[rr][2]) | ((unsigned int)f2bfu(c3 + a[rr][3]) << 16);
      res.z = (unsigned int)f2bfu(c4 + a[rr][4]) | ((unsigned int)f2bfu(c5 + a[rr][5]) << 16);
      res.w = (unsigned int)f2bfu(c6 + a[rr][6]) | ((unsigned int)f2bfu(c7 + a[rr][7]) << 16);
      *(uint4*)op = res;
    } else {
      float* op = (float*)out + oi;
      float4 o0 = *(float4*)op;
      float4 o1 = *(float4*)(op + 4);
      o0.x += a[rr][0]; o0.y += a[rr][1]; o0.z += a[rr][2]; o0.w += a[rr][3];
      o1.x += a[rr][4]; o1.y += a[rr][5]; o1.z += a[rr][6]; o1.w += a[rr][7];
      *(float4*)op = o0;
      *(float4*)(op + 4) = o1;
    }
  }
}

// ---------- launch ----------
extern "C" void kernel_launch(void* const* d_in, const int* in_sizes, int n_in,
                              void* d_out, int out_size, void* d_ws, size_t ws_size,
                              hipStream_t stream) {
  int chunks = 64;
  while (chunks > 1) {
    size_t need = (size_t)chunks * 64 * 4096 * 4 + 64 * 4096 * 2 + 4096 * 4 + 64;
    if (need <= ws_size) break;
    chunks >>= 1;
  }
  const int rows = LSEQ / chunks;

  float* kv_p = (float*)d_ws;
  unsigned short* kvb = (unsigned short*)(kv_p + (size_t)chunks * 64 * 4096);
  float* ksum = (float*)(kvb + 64 * 4096);
  int* flag = (int*)(ksum + 4096);

  hipMemsetAsync(ksum, 0, 4096 * sizeof(float), stream);
  detect_kernel<<<1, 64, 0, stream>>>((const unsigned int*)d_in[0], flag);
  kv_kernel<<<64 * chunks, 256, 0, stream>>>(
      d_in[1], d_in[2], d_in[3], kv_p, ksum, flag, chunks, rows);
  reduce_kernel<<<1024, 256, 0, stream>>>(kv_p, kvb, chunks);
  attn_kernel<<<4096, 256, 0, stream>>>(
      d_in[0], kvb, ksum, d_in[3], d_out, flag);
  conv_kernel<<<64 * 32, 256, 0, stream>>>(
      d_in[2], d_in[4], d_in[5], d_out, flag);
}

// Round 6
// 315.645 us; speedup vs baseline: 1.0624x; 1.0624x over previous
//
#include <hip/hip_runtime.h>

typedef __attribute__((ext_vector_type(8))) short short8;
typedef __attribute__((ext_vector_type(4))) float f32x4;

#define LSEQ   4096
#define NHEAD  8
#define DCH    64
#define HEIGHT 64
#define WIDTH  64

// ---------- helpers ----------
static __device__ __forceinline__ float bfu2f(unsigned short u) {
  return __uint_as_float(((unsigned int)u) << 16);
}
static __device__ __forceinline__ unsigned short f2bfu(float f) {
  unsigned int b = __float_as_uint(f);
  b += 0x7FFFu + ((b >> 16) & 1u);   // RNE
  return (unsigned short)(b >> 16);
}
static __device__ __forceinline__ float ldf(const void* p, int i, int isbf) {
  return isbf ? bfu2f(((const unsigned short*)p)[i]) : ((const float*)p)[i];
}
static __device__ __forceinline__ float softplus_inv(float sp) {
  float s = (sp > 20.f) ? sp : log1pf(expf(sp));
  return 1.f / s;
}
static __device__ __forceinline__ void unpack2(unsigned int u, float& lo, float& hi) {
  lo = __uint_as_float(u << 16);
  hi = __uint_as_float(u & 0xFFFF0000u);
}
// load 8 consecutive channels as floats (b128 for bf16, 2x b128 for fp32)
static __device__ __forceinline__ void load8(const void* p, int gi, int isbf, float o[8]) {
  if (isbf) {
    uint4 u = *(const uint4*)((const unsigned short*)p + gi);
    unpack2(u.x, o[0], o[1]); unpack2(u.y, o[2], o[3]);
    unpack2(u.z, o[4], o[5]); unpack2(u.w, o[6], o[7]);
  } else {
    const float4* f4 = (const float4*)((const float*)p + gi);
    float4 a = f4[0], b = f4[1];
    o[0]=a.x; o[1]=a.y; o[2]=a.z; o[3]=a.w;
    o[4]=b.x; o[5]=b.y; o[6]=b.z; o[7]=b.w;
  }
}
// reduce over the 8 lanes sharing a row (xor masks 1,2,4)
static __device__ __forceinline__ void row_reduce2(float& a, float& b) {
  #pragma unroll
  for (int m = 1; m < 8; m <<= 1) { a += __shfl_xor(a, m, 64); b += __shfl_xor(b, m, 64); }
}
static __device__ __forceinline__ float row_reduce1(float a) {
  #pragma unroll
  for (int m = 1; m < 8; m <<= 1) a += __shfl_xor(a, m, 64);
  return a;
}

// ---------- dtype detection ----------
__global__ void detect_kernel(const unsigned int* __restrict__ q, int* __restrict__ flag) {
  int lane = threadIdx.x & 63;
  int hits = 0;
  #pragma unroll
  for (int i = 0; i < 4; ++i) {
    unsigned int lo = q[lane * 4 + i] & 0xFFFFu;
    unsigned int e  = (lo >> 7) & 0xFFu;
    if (lo == 0u || (e >= 110u && e <= 140u)) hits++;
  }
  #pragma unroll
  for (int m = 1; m < 64; m <<= 1) hits += __shfl_xor(hits, m, 64);
  if (lane == 0) *flag = (hits > 128) ? 1 : 0;
}

// ---------- kv kernel ----------
// R6: upfront load issue. bf16 path stages ALL 4 subtiles of a group
// (8 x uint4 per thread, 16 KB/wave in flight) BEFORE any use; compiler's
// per-use vmcnt(N) overlaps subtile-0 processing with the remaining loads,
// and no memory issue waits behind a barrier. chunks=32 -> 2048 blocks,
// nsub=4 (one group). Double-buffered LDS, one barrier per subtile.
// LDS layout: transposed [d][s'] with s' = s ^ (((d>>3)&3)<<3).
__global__ __launch_bounds__(256) void kv_kernel(
    const void* __restrict__ keys, const void* __restrict__ values,
    const void* __restrict__ scale_param,
    float* __restrict__ kv_p, float* __restrict__ ksum_g,
    const int* __restrict__ flagp, int chunks, int rows)
{
  __shared__ __align__(16) unsigned short kfT[2][64 * 40];
  __shared__ __align__(16) unsigned short vvT[2][64 * 40];
  __shared__ float red[256];

  const int isbf = *flagp;
  const int b = blockIdx.x;
  const int chunk = b % chunks;
  const int nh = b / chunks;
  const int h = nh & 7, n = nh >> 3;
  const int t = threadIdx.x, lane = t & 63, wid = t >> 6;
  const int quad = lane >> 4, m16 = lane & 15;
  const int r = lane >> 3, c = lane & 7, d0 = c * 8;
  const int s_local = wid * 8 + r;
  const int sp = s_local ^ ((c & 3) << 3);

  float inv_s[8];
  #pragma unroll
  for (int i = 0; i < 8; ++i) inv_s[i] = softplus_inv(ldf(scale_param, d0 + i, isbf));

  f32x4 acc[4];
  #pragma unroll
  for (int mt = 0; mt < 4; ++mt) acc[mt] = (f32x4){0.f, 0.f, 0.f, 0.f};
  float ksum_acc[8];
  #pragma unroll
  for (int i = 0; i < 8; ++i) ksum_acc[i] = 0.f;

  const int nsub = rows >> 5;     // 128/chunks: multiple of 4 for chunks<=32

  // normalize kraw + ksum + transposed LDS write of kf into buffer `buf`
  auto norm_k = [&](const float kraw[8], int buf) {
    float xv[8], yv[8], s2 = 0.f, s6 = 0.f;
    #pragma unroll
    for (int i = 0; i < 8; ++i) {
      xv[i] = (fmaxf(kraw[i], 0.f) + 1e-6f) * inv_s[i];
      s2 += xv[i] * xv[i];
    }
    #pragma unroll
    for (int i = 0; i < 8; ++i) {
      yv[i] = xv[i] * xv[i] * xv[i];
      s6 += yv[i] * yv[i];
    }
    row_reduce2(s2, s6);
    const float coef = sqrtf(s2 / s6);
    #pragma unroll
    for (int i = 0; i < 8; ++i) {
      float f = yv[i] * coef;
      ksum_acc[i] += f;
      kfT[buf][(d0 + i) * 40 + sp] = f2bfu(f);
    }
  };
  // bf16: decode K, normalize; scatter V bytes directly
  auto procb = [&](uint4 K, uint4 V, int buf) {
    float kraw[8];
    unpack2(K.x, kraw[0], kraw[1]); unpack2(K.y, kraw[2], kraw[3]);
    unpack2(K.z, kraw[4], kraw[5]); unpack2(K.w, kraw[6], kraw[7]);
    norm_k(kraw, buf);
    unsigned short vs8[8];
    *(uint4*)vs8 = V;
    #pragma unroll
    for (int i = 0; i < 8; ++i) vvT[buf][(d0 + i) * 40 + sp] = vs8[i];
  };
  auto mfma_step = [&](int buf) {
    const int v = wid * 16 + m16;
    short8 bfr = *(const short8*)&vvT[buf][v * 40 + (quad ^ ((v >> 3) & 3)) * 8];
    #pragma unroll
    for (int mt = 0; mt < 4; ++mt) {
      int d = mt * 16 + m16;
      short8 afr = *(const short8*)&kfT[buf][d * 40 + (quad ^ ((d >> 3) & 3)) * 8];
      acc[mt] = __builtin_amdgcn_mfma_f32_16x16x32_bf16(afr, bfr, acc[mt], 0, 0, 0);
    }
  };

  if (isbf) {
    const unsigned short* kp = (const unsigned short*)keys;
    const unsigned short* vp = (const unsigned short*)values;
    uint4 k0, k1, k2, k3, v0, v1, v2, v3;   // named slots only (no arrays)
    for (int g = 0; g < nsub; g += 4) {
      const int s = chunk * rows + g * 32 + s_local;
      const size_t gi = ((size_t)(n * LSEQ + s) * NHEAD + h) * DCH + d0;
      // issue all 8 loads back-to-back (32 KB elem-stride between subtiles)
      k0 = *(const uint4*)(kp + gi);
      v0 = *(const uint4*)(vp + gi);
      k1 = *(const uint4*)(kp + gi + 16384);
      v1 = *(const uint4*)(vp + gi + 16384);
      k2 = *(const uint4*)(kp + gi + 32768);
      v2 = *(const uint4*)(vp + gi + 32768);
      k3 = *(const uint4*)(kp + gi + 49152);
      v3 = *(const uint4*)(vp + gi + 49152);
      procb(k0, v0, 0); __syncthreads();
      mfma_step(0); procb(k1, v1, 1); __syncthreads();
      mfma_step(1); procb(k2, v2, 0); __syncthreads();
      mfma_step(0); procb(k3, v3, 1); __syncthreads();
      mfma_step(1);
    }
  } else {
    // fp32 fallback: simple serial loop (correctness path; bench data is bf16)
    for (int sub = 0; sub < nsub; ++sub) {
      const int s = chunk * rows + sub * 32 + s_local;
      const int gi = ((n * LSEQ + s) * NHEAD + h) * DCH + d0;
      float kraw[8];
      load8(keys, gi, 0, kraw);
      norm_k(kraw, 0);
      float vraw[8];
      load8(values, gi, 0, vraw);
      #pragma unroll
      for (int i = 0; i < 8; ++i) vvT[0][(d0 + i) * 40 + sp] = f2bfu(vraw[i]);
      __syncthreads();
      mfma_step(0);
      __syncthreads();
    }
  }

  // fp32 partials: kv_p[chunk][nh][d][v]
  float* dst = kv_p + ((size_t)chunk * 64 + nh) * 4096;
  #pragma unroll
  for (int mt = 0; mt < 4; ++mt)
    #pragma unroll
    for (int rr = 0; rr < 4; ++rr) {
      int d = mt * 16 + quad * 4 + rr;
      dst[d * 64 + wid * 16 + m16] = acc[mt][rr];
    }

  // ksum: reduce across row-groups (masks 8,16,32), then block reduce + atomic
  #pragma unroll
  for (int i = 0; i < 8; ++i) {
    #pragma unroll
    for (int m = 8; m < 64; m <<= 1) ksum_acc[i] += __shfl_xor(ksum_acc[i], m, 64);
  }
  if (r == 0) {
    #pragma unroll
    for (int i = 0; i < 8; ++i) red[wid * 64 + d0 + i] = ksum_acc[i];
  }
  __syncthreads();
  if (t < 64) {
    float tot = red[t] + red[64 + t] + red[128 + t] + red[192 + t];
    atomicAdd(&ksum_g[nh * 64 + t], tot);
  }
}

// ---------- reduce: sum chunks, emit kv bf16 [nh][v][d] ----------
__global__ __launch_bounds__(256) void reduce_kernel(
    const float* __restrict__ kv_p, unsigned short* __restrict__ kvb, int chunks)
{
  int cidx = blockIdx.x * 256 + threadIdx.x;   // 0..262143
  int nh = cidx >> 12;
  int dv = cidx & 4095;
  int d = dv >> 6, v = dv & 63;
  float s = 0.f;
  for (int ch = 0; ch < chunks; ++ch)
    s += kv_p[((size_t)ch * 64 + nh) * 4096 + dv];
  kvb[(nh * 64 + v) * 64 + d] = f2bfu(s);
}

// ---------- attention kernel: per (n,h,y) MFMA O = (qf*z) @ kv ----------
__global__ __launch_bounds__(256) void attn_kernel(
    const void* __restrict__ queries, const unsigned short* __restrict__ kvb,
    const float* __restrict__ ksum_g, const void* __restrict__ scale_param,
    void* __restrict__ out, const int* __restrict__ flagp)
{
  __shared__ __align__(16) unsigned short qf[64 * 72];  // stride 36 dwords

  const int isbf = *flagp;
  const int b = blockIdx.x;
  const int y = b & 63;
  const int nh = b >> 6;
  const int h = nh & 7, n = nh >> 3;
  const int t = threadIdx.x, lane = t & 63, wid = t >> 6;
  const int quad = lane >> 4, m16 = lane & 15;
  const int r = lane >> 3, c = lane & 7, d0 = c * 8;

  float inv_s[8];
  #pragma unroll
  for (int i = 0; i < 8; ++i) inv_s[i] = softplus_inv(ldf(scale_param, d0 + i, isbf));
  float ks[8];
  {
    float4 k0 = *(const float4*)&ksum_g[nh * 64 + d0];
    float4 k1 = *(const float4*)&ksum_g[nh * 64 + d0 + 4];
    ks[0]=k0.x; ks[1]=k0.y; ks[2]=k0.z; ks[3]=k0.w;
    ks[4]=k1.x; ks[5]=k1.y; ks[6]=k1.z; ks[7]=k1.w;
  }

  // B fragments from global (L2-resident)
  const unsigned short* kvrow = kvb + (nh * 64 + wid * 16 + m16) * 64;
  short8 bfr0 = *(const short8*)&kvrow[quad * 8];
  short8 bfr1 = *(const short8*)&kvrow[32 + quad * 8];

  // stage qf: wave wid covers x = wid*16..+15 in 2 batches of 8 rows
  #pragma unroll
  for (int batch = 0; batch < 2; ++batch) {
    int x = wid * 16 + batch * 8 + r;
    int gi = ((n * LSEQ + y * 64 + x) * NHEAD + h) * DCH + d0;
    float qraw[8];
    load8(queries, gi, isbf, qraw);
    float xv[8], yv[8], s2 = 0.f, s6 = 0.f;
    #pragma unroll
    for (int i = 0; i < 8; ++i) {
      xv[i] = (fmaxf(qraw[i], 0.f) + 1e-6f) * inv_s[i];
      s2 += xv[i] * xv[i];
    }
    #pragma unroll
    for (int i = 0; i < 8; ++i) {
      yv[i] = xv[i] * xv[i] * xv[i];
      s6 += yv[i] * yv[i];
    }
    row_reduce2(s2, s6);
    const float coef = sqrtf(s2 / s6);
    float f[8], dot = 0.f;
    #pragma unroll
    for (int i = 0; i < 8; ++i) { f[i] = yv[i] * coef; dot += f[i] * ks[i]; }
    dot = row_reduce1(dot);
    const float z = 1.f / (dot + 1e-6f);
    uint4 pk;
    pk.x = (unsigned int)f2bfu(f[0] * z) | ((unsigned int)f2bfu(f[1] * z) << 16);
    pk.y = (unsigned int)f2bfu(f[2] * z) | ((unsigned int)f2bfu(f[3] * z) << 16);
    pk.z = (unsigned int)f2bfu(f[4] * z) | ((unsigned int)f2bfu(f[5] * z) << 16);
    pk.w = (unsigned int)f2bfu(f[6] * z) | ((unsigned int)f2bfu(f[7] * z) << 16);
    *(uint4*)&qf[x * 72 + d0] = pk;
  }
  __syncthreads();

  const size_t obase = (((size_t)n * LSEQ + y * 64) * NHEAD + h) * DCH;
  #pragma unroll
  for (int mt = 0; mt < 4; ++mt) {
    f32x4 acc = (f32x4){0.f, 0.f, 0.f, 0.f};
    short8 a0 = *(const short8*)&qf[(mt * 16 + m16) * 72 + quad * 8];
    short8 a1 = *(const short8*)&qf[(mt * 16 + m16) * 72 + 32 + quad * 8];
    acc = __builtin_amdgcn_mfma_f32_16x16x32_bf16(a0, bfr0, acc, 0, 0, 0);
    acc = __builtin_amdgcn_mfma_f32_16x16x32_bf16(a1, bfr1, acc, 0, 0, 0);
    #pragma unroll
    for (int rr = 0; rr < 4; ++rr) {
      int x = mt * 16 + quad * 4 + rr;
      int v = wid * 16 + m16;
      size_t oi = obase + (size_t)x * (NHEAD * DCH) + v;
      if (isbf) ((unsigned short*)out)[oi] = f2bfu(acc[rr]);
      else      ((float*)out)[oi] = acc[rr];
    }
  }
}

// ---------- conv kernel: depthwise 5x5 + bias, RMW on out ----------
// Channel-split: each block handles 32 of 64 channels for a 4-row slab.
// Compute/write map xx=t>>2, jb=t&3: lanes 0-3 RMW 64B contiguous (full
// sector). LDS read conflict-free: byte(l) = 16*l (jb-XOR permutes within
// each 64B group).
__global__ __launch_bounds__(256) void conv_kernel(
    const void* __restrict__ values, const void* __restrict__ dwc_w,
    const void* __restrict__ dwc_b, void* __restrict__ out,
    const int* __restrict__ flagp)
{
  __shared__ __align__(16) unsigned short vs[8 * 64 * 32];  // 32 KB
  __shared__ float wl[25 * 32];   // [tap][32 ch]
  __shared__ float bl[32];

  const int isbf = *flagp;
  const int b = blockIdx.x;
  const int slab = b & 15;
  const int half = (b >> 4) & 1;
  const int nh = b >> 5;
  const int h = nh & 7, n = nh >> 3;
  const int y0 = slab * 4;
  const int t = threadIdx.x;

  // weights for this half: global flat idx = (half*32+dloc)*25 + tap
  for (int i = t; i < 800; i += 256) {
    int dloc = i / 25, tap = i - dloc * 25;
    wl[tap * 32 + dloc] = ldf(dwc_w, half * 800 + i, isbf);
  }
  if (t < 32) bl[t] = ldf(dwc_b, half * 32 + t, isbf);

  // stage 8 rows (y0-2 .. y0+5) x 64 x x 32 ch as bf16
  for (int it = t; it < 8 * 64 * 4; it += 256) {
    int j = it & 3;                  // 8-ch sub-group within the half
    int xx = (it >> 2) & 63;
    int rr = it >> 8;
    int yy = y0 - 2 + rr;
    int swz = j ^ (xx & 3) ^ ((xx >> 2) & 3);
    unsigned short* dst = &vs[((rr * 64 + xx) * 32) + swz * 8];
    if (yy >= 0 && yy < HEIGHT) {
      int gi = ((n * LSEQ + yy * 64 + xx) * NHEAD + h) * DCH + half * 32 + j * 8;
      if (isbf) {
        *(uint4*)dst = *(const uint4*)((const unsigned short*)values + gi);
      } else {
        const float4* s4 = (const float4*)((const float*)values + gi);
        float4 f0 = s4[0], f1 = s4[1];
        dst[0] = f2bfu(f0.x); dst[1] = f2bfu(f0.y);
        dst[2] = f2bfu(f0.z); dst[3] = f2bfu(f0.w);
        dst[4] = f2bfu(f1.x); dst[5] = f2bfu(f1.y);
        dst[6] = f2bfu(f1.z); dst[7] = f2bfu(f1.w);
      }
    } else {
      uint4 z; z.x = z.y = z.z = z.w = 0u;
      *(uint4*)dst = z;
    }
  }
  __syncthreads();

  const int xx = t >> 2, jb = t & 3;   // coalesced RMW: 4 lanes cover 64B
  float a[4][8];
  float bias8[8];
  {
    float4 b0 = *(const float4*)&bl[jb * 8];
    float4 b1 = *(const float4*)&bl[jb * 8 + 4];
    bias8[0]=b0.x; bias8[1]=b0.y; bias8[2]=b0.z; bias8[3]=b0.w;
    bias8[4]=b1.x; bias8[5]=b1.y; bias8[6]=b1.z; bias8[7]=b1.w;
  }
  #pragma unroll
  for (int rr = 0; rr < 4; ++rr)
    #pragma unroll
    for (int cc = 0; cc < 8; ++cc) a[rr][cc] = bias8[cc];

  for (int ky = 0; ky < 5; ++ky) {
    #pragma unroll
    for (int kx = 0; kx < 5; ++kx) {
      int xs = xx + kx - 2;
      if ((unsigned)xs < (unsigned)WIDTH) {
        float4 w0 = *(const float4*)&wl[(ky * 5 + kx) * 32 + jb * 8];
        float4 w1 = *(const float4*)&wl[(ky * 5 + kx) * 32 + jb * 8 + 4];
        int swz = jb ^ (xs & 3) ^ ((xs >> 2) & 3);
        #pragma unroll
        for (int rr = 0; rr < 4; ++rr) {
          uint4 pv = *(const uint4*)&vs[(((rr + ky) * 64 + xs) * 32) + swz * 8];
          float v0,v1,v2,v3,v4,v5,v6,v7;
          unpack2(pv.x, v0, v1); unpack2(pv.y, v2, v3);
          unpack2(pv.z, v4, v5); unpack2(pv.w, v6, v7);
          a[rr][0] += w0.x * v0; a[rr][1] += w0.y * v1;
          a[rr][2] += w0.z * v2; a[rr][3] += w0.w * v3;
          a[rr][4] += w1.x * v4; a[rr][5] += w1.y * v5;
          a[rr][6] += w1.z * v6; a[rr][7] += w1.w * v7;
        }
      }
    }
  }
  #pragma unroll
  for (int rr = 0; rr < 4; ++rr) {
    size_t oi = (((size_t)n * LSEQ + (y0 + rr) * 64 + xx) * NHEAD + h) * DCH
              + half * 32 + jb * 8;
    if (isbf) {
      unsigned short* op = (unsigned short*)out + oi;
      uint4 cur = *(uint4*)op;
      float c0,c1,c2,c3,c4,c5,c6,c7;
      unpack2(cur.x, c0, c1); unpack2(cur.y, c2, c3);
      unpack2(cur.z, c4, c5); unpack2(cur.w, c6, c7);
      uint4 res;
      res.x = (unsigned int)f2bfu(c0 + a[rr][0]) | ((unsigned int)f2bfu(c1 + a[rr][1]) << 16);
      res.y = (unsigned int)f2bfu(c2 + a[rr][2]) | ((unsigned int)f2bfu(c3 + a[rr][3]) << 16);
      res.z = (unsigned int)f2bfu(c4 + a[rr][4]) | ((unsigned int)f2bfu(c5 + a[rr][5]) << 16);
      res.w = (unsigned int)f2bfu(c6 + a[rr][6]) | ((unsigned int)f2bfu(c7 + a[rr][7]) << 16);
      *(uint4*)op = res;
    } else {
      float* op = (float*)out + oi;
      float4 o0 = *(float4*)op;
      float4 o1 = *(float4*)(op + 4);
      o0.x += a[rr][0]; o0.y += a[rr][1]; o0.z += a[rr][2]; o0.w += a[rr][3];
      o1.x += a[rr][4]; o1.y += a[rr][5]; o1.z += a[rr][6]; o1.w += a[rr][7];
      *(float4*)op = o0;
      *(float4*)(op + 4) = o1;
    }
  }
}

// ---------- launch ----------
extern "C" void kernel_launch(void* const* d_in, const int* in_sizes, int n_in,
                              void* d_out, int out_size, void* d_ws, size_t ws_size,
                              hipStream_t stream) {
  int chunks = 32;
  while (chunks > 1) {
    size_t need = (size_t)chunks * 64 * 4096 * 4 + 64 * 4096 * 2 + 4096 * 4 + 64;
    if (need <= ws_size) break;
    chunks >>= 1;
  }
  const int rows = LSEQ / chunks;

  float* kv_p = (float*)d_ws;
  unsigned short* kvb = (unsigned short*)(kv_p + (size_t)chunks * 64 * 4096);
  float* ksum = (float*)(kvb + 64 * 4096);
  int* flag = (int*)(ksum + 4096);

  hipMemsetAsync(ksum, 0, 4096 * sizeof(float), stream);
  detect_kernel<<<1, 64, 0, stream>>>((const unsigned int*)d_in[0], flag);
  kv_kernel<<<64 * chunks, 256, 0, stream>>>(
      d_in[1], d_in[2], d_in[3], kv_p, ksum, flag, chunks, rows);
  reduce_kernel<<<1024, 256, 0, stream>>>(kv_p, kvb, chunks);
  attn_kernel<<<4096, 256, 0, stream>>>(
      d_in[0], kvb, ksum, d_in[3], d_out, flag);
  conv_kernel<<<64 * 32, 256, 0, stream>>>(
      d_in[2], d_in[4], d_in[5], d_out, flag);
}